// Round 11
// baseline (316.932 us; speedup 1.0000x reference)
//
#include <hip/hip_runtime.h>
#include <hip/hip_bf16.h>

#define NPG 258
#define DEG 8
#define EPG 2064          // NPG*DEG
#define CH 32
#define FIN 64
#define NB 1024
#define NTOT (NB * NPG)   // 264192
#define HID 128
#define KTOT 8256         // NPG*CH

typedef __attribute__((ext_vector_type(8))) short bf16x8;
typedef __attribute__((ext_vector_type(4))) float f32x4;

__device__ inline unsigned short f2bf(float f) {
    __hip_bfloat16 b = __float2bfloat16(f);
    return __builtin_bit_cast(unsigned short, b);
}
__device__ inline float bf2f(unsigned short u) {
    return __builtin_bit_cast(float, (unsigned)u << 16);
}
__device__ inline void cvt_split(const float4 a, const float4 b, bf16x8& hi, bf16x8& lo) {
    float f[8] = {a.x, a.y, a.z, a.w, b.x, b.y, b.z, b.w};
#pragma unroll
    for (int j = 0; j < 8; ++j) {
        unsigned short h = f2bf(f[j]);
        hi[j] = (short)h;
        lo[j] = (short)f2bf(f[j] - bf2f(h));
    }
}

// ---------------------------------------------------------------------------
// P: combined prep. Block 0: Wcat hi/lo split.  Blocks 1..129: Wd1 transpose.
// ---------------------------------------------------------------------------
__global__ __launch_bounds__(256) void prep(
    const float* __restrict__ W0, const float* __restrict__ W1,
    unsigned short* __restrict__ Wh, unsigned short* __restrict__ Wl,
    const float* __restrict__ Wd1, unsigned short* __restrict__ Wd1T)
{
    const int tid = threadIdx.x;
    if (blockIdx.x == 0) {
#pragma unroll
        for (int i = 0; i < 16; ++i) {
            const int idx = tid + i * 256;
            const int c = idx >> 6, k = idx & 63;
            const float v = (c < 32) ? W0[k * CH + c] : W1[k * CH + (c - 32)];
            const unsigned short h = f2bf(v);
            Wh[c * 64 + k] = h;
            Wl[c * 64 + k] = f2bf(v - bf2f(h));
        }
        return;
    }
    __shared__ float st[128][65];
    const int k0 = (blockIdx.x - 1) * 64;
#pragma unroll
    for (int i = 0; i < 32; ++i) {
        const int idx = tid + i * 256;
        const int kl = idx >> 7, cc = idx & 127;
        st[cc][kl] = Wd1[(size_t)(k0 + kl) * HID + cc];
    }
    __syncthreads();
    const int cc = tid >> 1, gq = tid & 1;
#pragma unroll
    for (int i = 0; i < 8; ++i) {
        const int ko = (gq + i * 2) * 4;
        ushort4 o;
        o.x = f2bf(st[cc][ko + 0]);
        o.y = f2bf(st[cc][ko + 1]);
        o.z = f2bf(st[cc][ko + 2]);
        o.w = f2bf(st[cc][ko + 3]);
        *reinterpret_cast<ushort4*>(Wd1T + (size_t)cc * KTOT + k0 + ko) = o;
    }
}

// ---------------------------------------------------------------------------
// K1: fused ChebConv, one block per graph (512 thr = 8 waves).
// v2 changes vs round 10:
//  - y0 stored bf16 (16.5 KB saved)
//  - slot arrays UNION'd over bsh/bsl (W tiles dead after GEMM; 16.4 KB saved)
//  - pass3 slot-fill atomic-free (pass1's atomicAdd return = within-row rank)
//  - gather loop 2-stage slot prefetch
//  LDS ~50.3 KB -> 3 blocks/CU (24 waves).
// ---------------------------------------------------------------------------
__global__ __launch_bounds__(512, 6) void conv_fused(
    const float* __restrict__ x, const int* __restrict__ esrc,
    const int* __restrict__ edst, const float* __restrict__ ew,
    const unsigned short* __restrict__ Wh, const unsigned short* __restrict__ Wl,
    const float* __restrict__ bc, unsigned short* __restrict__ h)
{
    __shared__ unsigned short y0s[NPG * CH];        // 16512 B (bf16)
    __shared__ unsigned short y1s[NPG * CH];        // 16512 B
    __shared__ __align__(16) char wbuf[16384];      // bsh/bsl; later slot_src/slot_w
    __shared__ int row_start[NPG + 1];              //  1036 B
    __shared__ int cursor[NPG];                     //  1032 B   => ~51.5 KB

    unsigned short* bsh = (unsigned short*)wbuf;            // [0, 8192)
    unsigned short* bsl = bsh + 4096;                       // [8192, 16384)
    unsigned short* slot_src = (unsigned short*)wbuf;       // [0, 4128)   (post-GEMM)
    float*          slot_w   = (float*)(wbuf + 4128);       // [4128, 12384)

    const int g   = blockIdx.x;
    const int tid = threadIdx.x;
    const int n0  = g * NPG;
    const long eb = (long)g * EPG;
    const long qb = (long)g * (NPG * CH);

    // stage swizzled Wcat + zero cursor
    {
        const int col = tid >> 3, o = tid & 7;
        const int so = o ^ (col & 7);
        *reinterpret_cast<uint4*>(&bsh[col * 64 + so * 8]) =
            *reinterpret_cast<const uint4*>(&Wh[col * 64 + o * 8]);
        *reinterpret_cast<uint4*>(&bsl[col * 64 + so * 8]) =
            *reinterpret_cast<const uint4*>(&Wl[col * 64 + o * 8]);
    }
    if (tid < NPG) cursor[tid] = 0;
    __syncthreads();

    // ---- phase A: edge load + histogram; atomicAdd return = within-row rank
    unsigned e_u[4];
    float    e_wv[4];
    int      e_p[4];
#pragma unroll
    for (int i = 0; i < 4; ++i) {
        const int e = tid + i * 512;               // 2048 < EPG always valid
        const int sl = esrc[eb + e] - n0;
        const int dl = edst[eb + e] - n0;
        e_u[i] = (unsigned)sl | ((unsigned)dl << 16);
        e_wv[i] = ew[eb + e];
        e_p[i] = atomicAdd(&cursor[dl], 1);
    }
    unsigned e_u4 = 0; float e_w4 = 0.f; int e_p4 = 0;
    const bool has4 = (tid < EPG - 2048);          // 16 tail edges
    if (has4) {
        const int e = tid + 2048;
        const int sl = esrc[eb + e] - n0;
        const int dl = edst[eb + e] - n0;
        e_u4 = (unsigned)sl | ((unsigned)dl << 16);
        e_w4 = ew[eb + e];
        e_p4 = atomicAdd(&cursor[dl], 1);
    }

    // ---- phase A2: GEMM 258x64 = x @ Wcat (17 row-tiles over 8 waves) ----
    const int w = tid >> 6, lane = tid & 63;
    const int r = lane & 15, kq = lane >> 4;
    for (int t = w; t < 17; t += 8) {
        const int rbase = t * 16;
        const int rowc = min(rbase + r, NPG - 1);  // clamp tail-tile loads
        const float* xp = x + (long)(n0 + rowc) * FIN + kq * 8;
        bf16x8 ah[2], al[2];
#pragma unroll
        for (int ks = 0; ks < 2; ++ks) {
            const float4 p0 = *reinterpret_cast<const float4*>(xp + ks * 32);
            const float4 p1 = *reinterpret_cast<const float4*>(xp + ks * 32 + 4);
            cvt_split(p0, p1, ah[ks], al[ks]);
        }
        f32x4 acc[4];
#pragma unroll
        for (int nt = 0; nt < 4; ++nt) acc[nt] = f32x4{0.f, 0.f, 0.f, 0.f};
#pragma unroll
        for (int nt = 0; nt < 4; ++nt) {
            const int col = nt * 16 + r;
            const int cs = col & 7;
#pragma unroll
            for (int ks = 0; ks < 2; ++ks) {
                const int gg = (ks * 4 + kq) ^ cs;
                const bf16x8 bh = *reinterpret_cast<const bf16x8*>(&bsh[col * 64 + gg * 8]);
                const bf16x8 bl = *reinterpret_cast<const bf16x8*>(&bsl[col * 64 + gg * 8]);
                acc[nt] = __builtin_amdgcn_mfma_f32_16x16x32_bf16(ah[ks], bh, acc[nt], 0, 0, 0);
                acc[nt] = __builtin_amdgcn_mfma_f32_16x16x32_bf16(ah[ks], bl, acc[nt], 0, 0, 0);
                acc[nt] = __builtin_amdgcn_mfma_f32_16x16x32_bf16(al[ks], bh, acc[nt], 0, 0, 0);
            }
        }
        // epilogue -> LDS (C/D: col=lane&15, row=(lane>>4)*4+rr)
#pragma unroll
        for (int rr = 0; rr < 4; ++rr) {
            const int row = rbase + kq * 4 + rr;
            if (row < NPG) {
                y0s[row * CH + r]      = f2bf(acc[0][rr]);
                y0s[row * CH + 16 + r] = f2bf(acc[1][rr]);
                y1s[row * CH + r]      = f2bf(acc[2][rr]);
                y1s[row * CH + 16 + r] = f2bf(acc[3][rr]);
            }
        }
    }
    __syncthreads();

    // ---- pass2: exclusive prefix scan of in-degrees (wave 0) ----
    if (tid < 64) {
        const int b0 = tid * 5;
        int loc[5], s = 0;
#pragma unroll
        for (int j = 0; j < 5; ++j) {
            const int idx = b0 + j;
            loc[j] = (idx < NPG) ? cursor[idx] : 0;
            s += loc[j];
        }
        int inc = s;
#pragma unroll
        for (int off = 1; off < 64; off <<= 1) {
            const int tshf = __shfl_up(inc, off, 64);
            if (tid >= off) inc += tshf;
        }
        int run = inc - s;
#pragma unroll
        for (int j = 0; j < 5; ++j) {
            const int idx = b0 + j;
            if (idx < NPG) row_start[idx] = run;
            run += loc[j];
        }
        if (tid == 63) row_start[NPG] = inc;
    }
    __syncthreads();    // also: all GEMM reads of bsh/bsl complete before here

    // ---- pass3: CSR slot fill, ATOMIC-FREE (slot = row_start + rank) ----
#pragma unroll
    for (int i = 0; i < 4; ++i) {
        const int slot = row_start[e_u[i] >> 16] + e_p[i];
        slot_src[slot] = (unsigned short)(e_u[i] & 0xFFFFu);
        slot_w[slot] = e_wv[i];
    }
    if (has4) {
        const int slot = row_start[e_u4 >> 16] + e_p4;
        slot_src[slot] = (unsigned short)(e_u4 & 0xFFFFu);
        slot_w[slot] = e_w4;
    }
    __syncthreads();

    // ---- pass4: gather. 32 groups x 16 lanes; lane = 2 channels ----
    const int grp = tid >> 4;                      // 0..31
    const int c = (tid & 15) * 2;
    const float b0 = bc[c], b1 = bc[c + 1];
#pragma unroll 1
    for (int p = 0; p < 9; ++p) {
        const int n = p * 32 + grp;
        if (n >= NPG) break;
        const int pb = row_start[n], pe = row_start[n + 1];
        float a0 = 0.f, a1 = 0.f;
        int us = (pb < pe) ? slot_src[pb] : 0;
        float wv = (pb < pe) ? slot_w[pb] : 0.f;
        for (int pos = pb; pos < pe; ++pos) {
            const int nx = pos + 1;
            const int us2 = (nx < pe) ? slot_src[nx] : 0;
            const float wv2 = (nx < pe) ? slot_w[nx] : 0.f;
            const unsigned u = *reinterpret_cast<const unsigned*>(&y1s[us * CH + c]);
            a0 += wv * bf2f((unsigned short)(u & 0xFFFFu));
            a1 += wv * bf2f((unsigned short)(u >> 16));
            us = us2; wv = wv2;
        }
        const unsigned u0 = *reinterpret_cast<const unsigned*>(&y0s[n * CH + c]);
        float v0 = bf2f((unsigned short)(u0 & 0xFFFFu)) + b0 + a0;
        float v1 = bf2f((unsigned short)(u0 >> 16)) + b1 + a1;
        v0 = (v0 > 0.f) ? v0 : expm1f(v0);
        v1 = (v1 > 0.f) ? v1 : expm1f(v1);
        const unsigned o = (unsigned)f2bf(v0) | ((unsigned)f2bf(v1) << 16);
        *reinterpret_cast<unsigned*>(&h[qb + (long)n * CH + c]) = o;
    }
}

// ---------------------------------------------------------------------------
// K2: dense_fused = GEMM1 (full-K, no split) + entire MLP tail, per 16 rows.
// 64 blocks x 512 thr (8 waves). Wave w: 16x16 MFMA tile, cols [16w,16w+16).
// A chunk staged in LDS (K=256); Wd1T read direct (L2-resident, 2.1 MB).
// Then h1 (16x128, LDS) -> relu -> 64 -> 32 -> 1 -> sigmoid, all in-block.
// Eliminates the 16.8 MB part buffer + one dispatch.
// ---------------------------------------------------------------------------
__global__ __launch_bounds__(512, 2) void dense_fused(
    const unsigned short* __restrict__ h, const unsigned short* __restrict__ Wd1T,
    const float* __restrict__ bd1, const float* __restrict__ Wd2,
    const float* __restrict__ bd2, const float* __restrict__ Wd3,
    const float* __restrict__ bd3, const float* __restrict__ Wd4,
    const float* __restrict__ bd4, float* __restrict__ out)
{
    __shared__ unsigned short As[16][264];   // 8448 B (K-chunk 256, +8 pad)
    __shared__ float h1s[16][128];           // 8192 B
    __shared__ float w2s[128 * 64];          // 32768 B
    __shared__ float w3s[64 * 32];           // 8192 B
    __shared__ float w4s[32];                // 128 B
    __shared__ float h2s[16][64];            // 4096 B
    __shared__ float h3s[16][32];            // 2048 B   => ~62.4 KB

    const int tid = threadIdx.x;
    const long m0 = (long)blockIdx.x * 16;
    const int w = tid >> 6, lane = tid & 63;
    const int r = lane & 15, kq = lane >> 4;
    const int c0 = w * 16;

    // stage MLP weights early (hides under GEMM)
    for (int i = tid; i < 128 * 64; i += 512) w2s[i] = Wd2[i];
    for (int i = tid; i < 64 * 32; i += 512)  w3s[i] = Wd3[i];
    if (tid < 32) w4s[tid] = Wd4[tid];

    f32x4 acc = {0.f, 0.f, 0.f, 0.f};
    const unsigned short* bp = Wd1T + (long)(c0 + r) * KTOT + kq * 8;
    const int arow = tid >> 5, aseg = tid & 31;

    for (int ch = 0; ch < 32; ++ch) {
        const int k0 = ch * 256;
        __syncthreads();
        *reinterpret_cast<uint4*>(&As[arow][aseg * 8]) =
            *reinterpret_cast<const uint4*>(&h[(m0 + arow) * KTOT + k0 + aseg * 8]);
        __syncthreads();
#pragma unroll
        for (int kb = 0; kb < 8; ++kb) {
            const bf16x8 a = *reinterpret_cast<const bf16x8*>(&As[r][kb * 32 + kq * 8]);
            const bf16x8 b = *reinterpret_cast<const bf16x8*>(bp + k0 + kb * 32);
            acc = __builtin_amdgcn_mfma_f32_16x16x32_bf16(a, b, acc, 0, 0, 0);
        }
    }
    // K tail: 8192..8255 (64 wide)
    __syncthreads();
    if (tid < 128) {
        const int row = tid >> 3, seg = tid & 7;
        *reinterpret_cast<uint4*>(&As[row][seg * 8]) =
            *reinterpret_cast<const uint4*>(&h[(m0 + row) * KTOT + 8192 + seg * 8]);
    }
    __syncthreads();
#pragma unroll
    for (int kb = 0; kb < 2; ++kb) {
        const bf16x8 a = *reinterpret_cast<const bf16x8*>(&As[r][kb * 32 + kq * 8]);
        const bf16x8 b = *reinterpret_cast<const bf16x8*>(bp + 8192 + kb * 32);
        acc = __builtin_amdgcn_mfma_f32_16x16x32_bf16(a, b, acc, 0, 0, 0);
    }

    // h1 epilogue: + bd1, relu  (C/D: col=lane&15, row=(lane>>4)*4+rr)
    const float b1v = bd1[c0 + r];
#pragma unroll
    for (int rr = 0; rr < 4; ++rr)
        h1s[kq * 4 + rr][c0 + r] = fmaxf(acc[rr] + b1v, 0.f);
    __syncthreads();

    // layer2: 128 -> 64
    for (int idx = tid; idx < 16 * 64; idx += 512) {
        const int rr = idx >> 6, j = idx & 63;
        float s = bd2[j];
#pragma unroll 8
        for (int k = 0; k < 128; ++k) s += h1s[rr][k] * w2s[k * 64 + j];
        h2s[rr][j] = fmaxf(s, 0.f);
    }
    __syncthreads();

    // layer3: 64 -> 32  (512 = 16 rows x 32 cols exactly)
    {
        const int rr = tid >> 5, j = tid & 31;
        float s = bd3[j];
#pragma unroll 8
        for (int k = 0; k < 64; ++k) s += h2s[rr][k] * w3s[k * 32 + j];
        h3s[rr][j] = fmaxf(s, 0.f);
    }
    __syncthreads();

    // layer4: dot(32) + sigmoid
    if (tid < 16) {
        float s = 0.f;
#pragma unroll
        for (int k = 0; k < 32; ++k) s += h3s[tid][k] * w4s[k];
        out[m0 + tid] = 1.f / (1.f + expf(-(s + bd4[0])));
    }
}

// ---------------------------------------------------------------------------
extern "C" void kernel_launch(void* const* d_in, const int* in_sizes, int n_in,
                              void* d_out, int out_size, void* d_ws, size_t ws_size,
                              hipStream_t stream)
{
    const float* x    = (const float*)d_in[0];
    const int*   esrc = (const int*)d_in[1];
    const int*   edst = (const int*)d_in[2];
    const float* ew   = (const float*)d_in[3];
    const float* W0   = (const float*)d_in[4];
    const float* W1   = (const float*)d_in[5];
    const float* bc   = (const float*)d_in[6];
    const float* Wd1  = (const float*)d_in[7];
    const float* bd1  = (const float*)d_in[8];
    const float* Wd2  = (const float*)d_in[9];
    const float* bd2  = (const float*)d_in[10];
    const float* Wd3  = (const float*)d_in[11];
    const float* bd3  = (const float*)d_in[12];
    const float* Wd4  = (const float*)d_in[13];
    const float* bd4  = (const float*)d_in[14];
    float* out = (float*)d_out;

    // ws: h bf16 @0 (16,908,288) | wd1t bf16 @16908288 (2,113,536)
    //     wch @19021824 (8192) | wcl @19030016 (8192)
    char* wsb = (char*)d_ws;
    unsigned short* h    = (unsigned short*)wsb;
    unsigned short* wd1t = (unsigned short*)(wsb + 16908288);
    unsigned short* wch  = (unsigned short*)(wsb + 19021824);
    unsigned short* wcl  = (unsigned short*)(wsb + 19030016);

    prep<<<1 + KTOT / 64, 256, 0, stream>>>(W0, W1, wch, wcl, Wd1, wd1t);
    conv_fused<<<NB, 512, 0, stream>>>(x, esrc, edst, ew, wch, wcl, bc, h);
    dense_fused<<<NB / 16, 512, 0, stream>>>(h, wd1t, bd1, Wd2, bd2, Wd3, bd3, Wd4, bd4, out);
}

// Round 12
// 297.603 us; speedup vs baseline: 1.0649x; 1.0649x over previous
//
#include <hip/hip_runtime.h>
#include <hip/hip_bf16.h>

#define NPG 258
#define DEG 8
#define EPG 2064          // NPG*DEG
#define CH 32
#define FIN 64
#define NB 1024
#define NTOT (NB * NPG)   // 264192
#define HID 128
#define KTOT 8256         // NPG*CH

typedef __attribute__((ext_vector_type(8))) short bf16x8;
typedef __attribute__((ext_vector_type(4))) float f32x4;

__device__ inline unsigned short f2bf(float f) {
    __hip_bfloat16 b = __float2bfloat16(f);
    return __builtin_bit_cast(unsigned short, b);
}
__device__ inline float bf2f(unsigned short u) {
    return __builtin_bit_cast(float, (unsigned)u << 16);
}
__device__ inline void cvt_split(const float4 a, const float4 b, bf16x8& hi, bf16x8& lo) {
    float f[8] = {a.x, a.y, a.z, a.w, b.x, b.y, b.z, b.w};
#pragma unroll
    for (int j = 0; j < 8; ++j) {
        unsigned short h = f2bf(f[j]);
        hi[j] = (short)h;
        lo[j] = (short)f2bf(f[j] - bf2f(h));
    }
}

// ---------------------------------------------------------------------------
// P: combined prep. Block 0: Wcat hi/lo split.  Blocks 1..129: Wd1 transpose.
// ---------------------------------------------------------------------------
__global__ __launch_bounds__(256) void prep(
    const float* __restrict__ W0, const float* __restrict__ W1,
    unsigned short* __restrict__ Wh, unsigned short* __restrict__ Wl,
    const float* __restrict__ Wd1, unsigned short* __restrict__ Wd1T)
{
    const int tid = threadIdx.x;
    if (blockIdx.x == 0) {
#pragma unroll
        for (int i = 0; i < 16; ++i) {
            const int idx = tid + i * 256;
            const int c = idx >> 6, k = idx & 63;
            const float v = (c < 32) ? W0[k * CH + c] : W1[k * CH + (c - 32)];
            const unsigned short h = f2bf(v);
            Wh[c * 64 + k] = h;
            Wl[c * 64 + k] = f2bf(v - bf2f(h));
        }
        return;
    }
    __shared__ float st[128][65];
    const int k0 = (blockIdx.x - 1) * 64;
#pragma unroll
    for (int i = 0; i < 32; ++i) {
        const int idx = tid + i * 256;
        const int kl = idx >> 7, cc = idx & 127;
        st[cc][kl] = Wd1[(size_t)(k0 + kl) * HID + cc];
    }
    __syncthreads();
    const int cc = tid >> 1, gq = tid & 1;
#pragma unroll
    for (int i = 0; i < 8; ++i) {
        const int ko = (gq + i * 2) * 4;
        ushort4 o;
        o.x = f2bf(st[cc][ko + 0]);
        o.y = f2bf(st[cc][ko + 1]);
        o.z = f2bf(st[cc][ko + 2]);
        o.w = f2bf(st[cc][ko + 3]);
        *reinterpret_cast<ushort4*>(Wd1T + (size_t)cc * KTOT + k0 + ko) = o;
    }
}

// ---------------------------------------------------------------------------
// K1: fused ChebConv, one block per graph (512 thr = 8 waves).
// Same as round 11 EXCEPT __launch_bounds__(512,4): the (512,6) bound forced
// VGPR 64->40 via scratch spills (+200 MB HBM scratch traffic = the round-11
// regression). LDS ~51.5 KB -> up to 3 blocks/CU; let the allocator breathe.
// ---------------------------------------------------------------------------
__global__ __launch_bounds__(512, 4) void conv_fused(
    const float* __restrict__ x, const int* __restrict__ esrc,
    const int* __restrict__ edst, const float* __restrict__ ew,
    const unsigned short* __restrict__ Wh, const unsigned short* __restrict__ Wl,
    const float* __restrict__ bc, unsigned short* __restrict__ h)
{
    __shared__ unsigned short y0s[NPG * CH];        // 16512 B (bf16)
    __shared__ unsigned short y1s[NPG * CH];        // 16512 B
    __shared__ __align__(16) char wbuf[16384];      // bsh/bsl; later slot_src/slot_w
    __shared__ int row_start[NPG + 1];              //  1036 B
    __shared__ int cursor[NPG];                     //  1032 B   => ~51.5 KB

    unsigned short* bsh = (unsigned short*)wbuf;            // [0, 8192)
    unsigned short* bsl = bsh + 4096;                       // [8192, 16384)
    unsigned short* slot_src = (unsigned short*)wbuf;       // [0, 4128)   (post-GEMM)
    float*          slot_w   = (float*)(wbuf + 4128);       // [4128, 12384)

    const int g   = blockIdx.x;
    const int tid = threadIdx.x;
    const int n0  = g * NPG;
    const long eb = (long)g * EPG;
    const long qb = (long)g * (NPG * CH);

    // stage swizzled Wcat + zero cursor
    {
        const int col = tid >> 3, o = tid & 7;
        const int so = o ^ (col & 7);
        *reinterpret_cast<uint4*>(&bsh[col * 64 + so * 8]) =
            *reinterpret_cast<const uint4*>(&Wh[col * 64 + o * 8]);
        *reinterpret_cast<uint4*>(&bsl[col * 64 + so * 8]) =
            *reinterpret_cast<const uint4*>(&Wl[col * 64 + o * 8]);
    }
    if (tid < NPG) cursor[tid] = 0;
    __syncthreads();

    // ---- phase A: edge load + histogram; atomicAdd return = within-row rank
    unsigned e_u[4];
    float    e_wv[4];
    int      e_p[4];
#pragma unroll
    for (int i = 0; i < 4; ++i) {
        const int e = tid + i * 512;               // 2048 < EPG always valid
        const int sl = esrc[eb + e] - n0;
        const int dl = edst[eb + e] - n0;
        e_u[i] = (unsigned)sl | ((unsigned)dl << 16);
        e_wv[i] = ew[eb + e];
        e_p[i] = atomicAdd(&cursor[dl], 1);
    }
    unsigned e_u4 = 0; float e_w4 = 0.f; int e_p4 = 0;
    const bool has4 = (tid < EPG - 2048);          // 16 tail edges
    if (has4) {
        const int e = tid + 2048;
        const int sl = esrc[eb + e] - n0;
        const int dl = edst[eb + e] - n0;
        e_u4 = (unsigned)sl | ((unsigned)dl << 16);
        e_w4 = ew[eb + e];
        e_p4 = atomicAdd(&cursor[dl], 1);
    }

    // ---- phase A2: GEMM 258x64 = x @ Wcat (17 row-tiles over 8 waves) ----
    const int w = tid >> 6, lane = tid & 63;
    const int r = lane & 15, kq = lane >> 4;
    for (int t = w; t < 17; t += 8) {
        const int rbase = t * 16;
        const int rowc = min(rbase + r, NPG - 1);  // clamp tail-tile loads
        const float* xp = x + (long)(n0 + rowc) * FIN + kq * 8;
        bf16x8 ah[2], al[2];
#pragma unroll
        for (int ks = 0; ks < 2; ++ks) {
            const float4 p0 = *reinterpret_cast<const float4*>(xp + ks * 32);
            const float4 p1 = *reinterpret_cast<const float4*>(xp + ks * 32 + 4);
            cvt_split(p0, p1, ah[ks], al[ks]);
        }
        f32x4 acc[4];
#pragma unroll
        for (int nt = 0; nt < 4; ++nt) acc[nt] = f32x4{0.f, 0.f, 0.f, 0.f};
#pragma unroll
        for (int nt = 0; nt < 4; ++nt) {
            const int col = nt * 16 + r;
            const int cs = col & 7;
#pragma unroll
            for (int ks = 0; ks < 2; ++ks) {
                const int gg = (ks * 4 + kq) ^ cs;
                const bf16x8 bh = *reinterpret_cast<const bf16x8*>(&bsh[col * 64 + gg * 8]);
                const bf16x8 bl = *reinterpret_cast<const bf16x8*>(&bsl[col * 64 + gg * 8]);
                acc[nt] = __builtin_amdgcn_mfma_f32_16x16x32_bf16(ah[ks], bh, acc[nt], 0, 0, 0);
                acc[nt] = __builtin_amdgcn_mfma_f32_16x16x32_bf16(ah[ks], bl, acc[nt], 0, 0, 0);
                acc[nt] = __builtin_amdgcn_mfma_f32_16x16x32_bf16(al[ks], bh, acc[nt], 0, 0, 0);
            }
        }
        // epilogue -> LDS (C/D: col=lane&15, row=(lane>>4)*4+rr)
#pragma unroll
        for (int rr = 0; rr < 4; ++rr) {
            const int row = rbase + kq * 4 + rr;
            if (row < NPG) {
                y0s[row * CH + r]      = f2bf(acc[0][rr]);
                y0s[row * CH + 16 + r] = f2bf(acc[1][rr]);
                y1s[row * CH + r]      = f2bf(acc[2][rr]);
                y1s[row * CH + 16 + r] = f2bf(acc[3][rr]);
            }
        }
    }
    __syncthreads();

    // ---- pass2: exclusive prefix scan of in-degrees (wave 0) ----
    if (tid < 64) {
        const int b0 = tid * 5;
        int loc[5], s = 0;
#pragma unroll
        for (int j = 0; j < 5; ++j) {
            const int idx = b0 + j;
            loc[j] = (idx < NPG) ? cursor[idx] : 0;
            s += loc[j];
        }
        int inc = s;
#pragma unroll
        for (int off = 1; off < 64; off <<= 1) {
            const int tshf = __shfl_up(inc, off, 64);
            if (tid >= off) inc += tshf;
        }
        int run = inc - s;
#pragma unroll
        for (int j = 0; j < 5; ++j) {
            const int idx = b0 + j;
            if (idx < NPG) row_start[idx] = run;
            run += loc[j];
        }
        if (tid == 63) row_start[NPG] = inc;
    }
    __syncthreads();    // also: all GEMM reads of bsh/bsl complete before here

    // ---- pass3: CSR slot fill, ATOMIC-FREE (slot = row_start + rank) ----
#pragma unroll
    for (int i = 0; i < 4; ++i) {
        const int slot = row_start[e_u[i] >> 16] + e_p[i];
        slot_src[slot] = (unsigned short)(e_u[i] & 0xFFFFu);
        slot_w[slot] = e_wv[i];
    }
    if (has4) {
        const int slot = row_start[e_u4 >> 16] + e_p4;
        slot_src[slot] = (unsigned short)(e_u4 & 0xFFFFu);
        slot_w[slot] = e_w4;
    }
    __syncthreads();

    // ---- pass4: gather. 32 groups x 16 lanes; lane = 2 channels ----
    const int grp = tid >> 4;                      // 0..31
    const int c = (tid & 15) * 2;
    const float b0 = bc[c], b1 = bc[c + 1];
#pragma unroll 1
    for (int p = 0; p < 9; ++p) {
        const int n = p * 32 + grp;
        if (n >= NPG) break;
        const int pb = row_start[n], pe = row_start[n + 1];
        float a0 = 0.f, a1 = 0.f;
        int us = (pb < pe) ? slot_src[pb] : 0;
        float wv = (pb < pe) ? slot_w[pb] : 0.f;
        for (int pos = pb; pos < pe; ++pos) {
            const int nx = pos + 1;
            const int us2 = (nx < pe) ? slot_src[nx] : 0;
            const float wv2 = (nx < pe) ? slot_w[nx] : 0.f;
            const unsigned u = *reinterpret_cast<const unsigned*>(&y1s[us * CH + c]);
            a0 += wv * bf2f((unsigned short)(u & 0xFFFFu));
            a1 += wv * bf2f((unsigned short)(u >> 16));
            us = us2; wv = wv2;
        }
        const unsigned u0 = *reinterpret_cast<const unsigned*>(&y0s[n * CH + c]);
        float v0 = bf2f((unsigned short)(u0 & 0xFFFFu)) + b0 + a0;
        float v1 = bf2f((unsigned short)(u0 >> 16)) + b1 + a1;
        v0 = (v0 > 0.f) ? v0 : expm1f(v0);
        v1 = (v1 > 0.f) ? v1 : expm1f(v1);
        const unsigned o = (unsigned)f2bf(v0) | ((unsigned)f2bf(v1) << 16);
        *reinterpret_cast<unsigned*>(&h[qb + (long)n * CH + c]) = o;
    }
}

// ---------------------------------------------------------------------------
// K2: dense_fused v2 = GEMM1 + full MLP tail, per 4 output rows.
// 256 blocks x 512 thr -> 1 block/CU, ALL CUs busy (v1's 64 blocks left 75%
// of the chip idle). Direct-from-global A and B (gemm1-proven pattern, zero
// K-loop barriers). Wave w: 16x16 MFMA tile cols [16w,16w+16), full K; only
// C rows 0..3 kept (A rows 4..15 are neighbor rows, L1/L3-absorbed).
// MLP weights staged bf16 in LDS (~26 KB total).
// ---------------------------------------------------------------------------
__global__ __launch_bounds__(512, 2) void dense_fused(
    const unsigned short* __restrict__ h, const unsigned short* __restrict__ Wd1T,
    const float* __restrict__ bd1, const float* __restrict__ Wd2,
    const float* __restrict__ bd2, const float* __restrict__ Wd3,
    const float* __restrict__ bd3, const float* __restrict__ Wd4,
    const float* __restrict__ bd4, float* __restrict__ out)
{
    __shared__ float h1s[4][128];            // 2048 B
    __shared__ unsigned short w2s[128 * 64]; // 16384 B (bf16)
    __shared__ unsigned short w3s[64 * 32];  // 4096 B (bf16)
    __shared__ float w4s[32];                // 128 B
    __shared__ float h2s[4][64];             // 1024 B
    __shared__ float h3s[4][32];             // 512 B   => ~24.2 KB

    const int tid = threadIdx.x;
    const long m0 = (long)blockIdx.x * 4;
    const int w = tid >> 6, lane = tid & 63;
    const int r = lane & 15, kq = lane >> 4;
    const int c0 = w * 16;

    // stage MLP weights (bf16) — hides under the GEMM's first loads
    for (int i = tid; i < 128 * 64; i += 512) w2s[i] = f2bf(Wd2[i]);
    for (int i = tid; i < 64 * 32; i += 512)  w3s[i] = f2bf(Wd3[i]);
    if (tid < 32) w4s[tid] = Wd4[tid];

    // GEMM: row = m0 + r (A rows 4..15 are neighbor rows; outputs discarded)
    const long rowA = min(m0 + r, (long)(NB - 1));
    const unsigned short* ap = h + rowA * KTOT + kq * 8;
    const unsigned short* bp = Wd1T + (long)(c0 + r) * KTOT + kq * 8;

    f32x4 acc = {0.f, 0.f, 0.f, 0.f};
#pragma unroll 8
    for (int ks = 0; ks < 258; ++ks) {
        const int k = ks * 32;
        const bf16x8 a = *reinterpret_cast<const bf16x8*>(ap + k);
        const bf16x8 b = *reinterpret_cast<const bf16x8*>(bp + k);
        acc = __builtin_amdgcn_mfma_f32_16x16x32_bf16(a, b, acc, 0, 0, 0);
    }

    // h1: rows 0..3 (kq==0 lanes), +bias, relu
    if (kq == 0) {
        const float b1v = bd1[c0 + r];
#pragma unroll
        for (int rr = 0; rr < 4; ++rr)
            h1s[rr][c0 + r] = fmaxf(acc[rr] + b1v, 0.f);
    }
    __syncthreads();

    // layer2: 128 -> 64  (4 rows x 64 cols = 256 threads)
    if (tid < 256) {
        const int rr = tid >> 6, j = tid & 63;
        float s = bd2[j];
#pragma unroll 8
        for (int k = 0; k < 128; ++k) s += h1s[rr][k] * bf2f(w2s[k * 64 + j]);
        h2s[rr][j] = fmaxf(s, 0.f);
    }
    __syncthreads();

    // layer3: 64 -> 32  (4 x 32 = 128 threads)
    if (tid < 128) {
        const int rr = tid >> 5, j = tid & 31;
        float s = bd3[j];
#pragma unroll 8
        for (int k = 0; k < 64; ++k) s += h2s[rr][k] * bf2f(w3s[k * 32 + j]);
        h3s[rr][j] = fmaxf(s, 0.f);
    }
    __syncthreads();

    // layer4: dot(32) + sigmoid
    if (tid < 4) {
        float s = 0.f;
#pragma unroll
        for (int k = 0; k < 32; ++k) s += h3s[tid][k] * w4s[k];
        out[m0 + tid] = 1.f / (1.f + expf(-(s + bd4[0])));
    }
}

// ---------------------------------------------------------------------------
extern "C" void kernel_launch(void* const* d_in, const int* in_sizes, int n_in,
                              void* d_out, int out_size, void* d_ws, size_t ws_size,
                              hipStream_t stream)
{
    const float* x    = (const float*)d_in[0];
    const int*   esrc = (const int*)d_in[1];
    const int*   edst = (const int*)d_in[2];
    const float* ew   = (const float*)d_in[3];
    const float* W0   = (const float*)d_in[4];
    const float* W1   = (const float*)d_in[5];
    const float* bc   = (const float*)d_in[6];
    const float* Wd1  = (const float*)d_in[7];
    const float* bd1  = (const float*)d_in[8];
    const float* Wd2  = (const float*)d_in[9];
    const float* bd2  = (const float*)d_in[10];
    const float* Wd3  = (const float*)d_in[11];
    const float* bd3  = (const float*)d_in[12];
    const float* Wd4  = (const float*)d_in[13];
    const float* bd4  = (const float*)d_in[14];
    float* out = (float*)d_out;

    // ws: h bf16 @0 (16,908,288) | wd1t bf16 @16908288 (2,113,536)
    //     wch @19021824 (8192) | wcl @19030016 (8192)
    char* wsb = (char*)d_ws;
    unsigned short* h    = (unsigned short*)wsb;
    unsigned short* wd1t = (unsigned short*)(wsb + 16908288);
    unsigned short* wch  = (unsigned short*)(wsb + 19021824);
    unsigned short* wcl  = (unsigned short*)(wsb + 19030016);

    prep<<<1 + KTOT / 64, 256, 0, stream>>>(W0, W1, wch, wcl, Wd1, wd1t);
    conv_fused<<<NB, 512, 0, stream>>>(x, esrc, edst, ew, wch, wcl, bc, h);
    dense_fused<<<NB / 4, 512, 0, stream>>>(h, wd1t, bd1, Wd2, bd2, Wd3, bd3, Wd4, bd4, out);
}